// Round 2
// 358.660 us; speedup vs baseline: 1.0493x; 1.0493x over previous
//
#include <hip/hip_runtime.h>
#include <stdint.h>

typedef __attribute__((ext_vector_type(4))) float f32x4;
typedef __attribute__((ext_vector_type(8))) short s16x8;

struct Params {
  const float* cls_feat[3];
  const float* reg_feat[3];
  const float* obj_w[3];
  const float* obj_b[3];
  const float* cls_w[3];
  const float* cls_b[3];
  const float* reg_w[3];
  const float* reg_b[3];
  float* out;
};

__device__ __forceinline__ unsigned short f2bf(float f) {
  unsigned int u = __builtin_bit_cast(unsigned int, f);
  u = (u + 0x7FFFu + ((u >> 16) & 1u)) >> 16;  // RNE
  return (unsigned short)u;
}

// m-tile = 80: 6400/1600/400 all divide evenly -> no partial tiles.
// LDS: [m][k] bf16, pitch 256 shorts (512 B) with 16B-chunk XOR swizzle
// (chunk ^= m&7): 40960 B exactly -> 4 blocks/CU; reads & writes 2-way (free).
__global__ __launch_bounds__(320, 5) void head_kernel(Params p) {
  const int tid  = threadIdx.x;
  const int lane = tid & 63;
  const int wave = tid >> 6;      // 0..4, one 16-row o-tile each
  const int quad = lane >> 4;     // 0..3
  const int col  = lane & 15;
  const bool is_cls = (blockIdx.y == 0);

  // block -> (batch, level, m-tile). 105 tiles/batch: 80 + 20 + 5
  int bx = blockIdx.x;
  int b  = bx / 105;
  int t  = bx - b * 105;
  int level, tloc;
  if (t < 80)       { level = 0; tloc = t; }
  else if (t < 100) { level = 1; tloc = t - 80; }
  else              { level = 2; tloc = t - 100; }

  const int   LW_[3]   = {80, 40, 20};
  const int   LM_[3]   = {6400, 1600, 400};
  const float LS_[3]   = {8.f, 16.f, 32.f};
  const int   LOFF_[3] = {0, 6400, 8000};

  const int   Mlvl = LM_[level];
  const int   Moff = LOFF_[level];
  const float strd = LS_[level];
  const int   m0   = tloc * 80;

  __shared__ __align__(16) short lds_feat[80 * 256];  // 40960 B

  const f32x4 vzero = {0.f, 0.f, 0.f, 0.f};

  // ---- weights: issue ALL loads first (FIFO-oldest; L2-resident after first touch) ----
  const int orow = wave * 16 + col;
  const float* wptr;
  if (is_cls)          wptr = p.cls_w[level] + orow * 256;
  else if (orow < 64)  wptr = p.reg_w[level] + orow * 256;
  else if (orow == 64) wptr = p.obj_w[level];
  else                 wptr = nullptr;

  f32x4 wv[16];
  #pragma unroll
  for (int s = 0; s < 8; ++s) {
    if (wptr) {
      const f32x4* wp = (const f32x4*)(wptr + s * 32 + quad * 8);
      wv[2 * s]     = wp[0];
      wv[2 * s + 1] = wp[1];
    } else {
      wv[2 * s]     = vzero;
      wv[2 * s + 1] = vzero;
    }
  }

  f32x4 bias = vzero;
  {
    const int o0 = wave * 16 + quad * 4;
    if (is_cls)        bias = *(const f32x4*)(p.cls_b[level] + o0);
    else if (o0 < 64)  bias = *(const f32x4*)(p.reg_b[level] + o0);
    else if (o0 == 64) bias[0] = p.obj_b[level][0];
  }

  // ---- feature staging: uniform 8 groups x 8 ch per thread, 2-deep pipeline ----
  // thread -> column mloc (fixed), channel groups cb = cb0 + 4*i, i = 0..7
  const int mloc = tid % 80;
  const int cb0  = tid / 80;  // 0..3
  const float* featp = (is_cls ? p.cls_feat[level] : p.reg_feat[level])
                       + (size_t)b * 256 * (size_t)Mlvl + m0 + mloc;

  float f[2][8];
  #pragma unroll
  for (int j = 0; j < 8; ++j) f[0][j] = featp[(size_t)(cb0 * 8 + j) * Mlvl];

  // convert weights while feature group 0 is in flight
  s16x8 afrag[8];
  #pragma unroll
  for (int s = 0; s < 8; ++s) {
    s16x8 a;
    #pragma unroll
    for (int j = 0; j < 4; ++j) {
      a[j]     = (short)f2bf(wv[2 * s][j]);
      a[4 + j] = (short)f2bf(wv[2 * s + 1][j]);
    }
    afrag[s] = a;
  }

  const int swz = mloc & 7;
  #pragma unroll
  for (int i = 0; i < 8; ++i) {
    if (i < 7) {  // issue next group before consuming current -> keeps 8+ loads in flight
      const int cbn = cb0 + 4 * (i + 1);
      #pragma unroll
      for (int j = 0; j < 8; ++j)
        f[(i + 1) & 1][j] = featp[(size_t)(cbn * 8 + j) * Mlvl];
    }
    const int cb = cb0 + 4 * i;
    s16x8 h;
    #pragma unroll
    for (int j = 0; j < 8; ++j) h[j] = (short)f2bf(f[i & 1][j]);
    *(s16x8*)&lds_feat[mloc * 256 + ((cb ^ swz) << 3)] = h;
  }

  __syncthreads();

  // ---- GEMM: D[o][m] = W[o][k] * feat[k][m], K=256, 5 m-frags/wave ----
  f32x4 acc[5];
  #pragma unroll
  for (int mf = 0; mf < 5; ++mf) acc[mf] = vzero;
  #pragma unroll
  for (int mf = 0; mf < 5; ++mf) {
    const int row = mf * 16 + col;
    const short* base = &lds_feat[row * 256];
    const int rswz = row & 7;  // == col&7
    #pragma unroll
    for (int s = 0; s < 8; ++s) {
      s16x8 bfrag = *(const s16x8*)(base + (((s * 4 + quad) ^ rswz) << 3));
      acc[mf] = __builtin_amdgcn_mfma_f32_16x16x32_bf16(afrag[s], bfrag, acc[mf], 0, 0, 0);
    }
  }

  // ---- epilogue ----
  const size_t outbase = (size_t)b * 8400 + Moff + m0;
  float* out = p.out;

  if (is_cls) {
    #pragma unroll
    for (int mf = 0; mf < 5; ++mf) {
      const int m = mf * 16 + col;
      f32x4 v = acc[mf] + bias;
      float* dst = out + (outbase + m) * 149 + 1 + wave * 16 + quad * 4;
      __builtin_memcpy(dst, &v, 16);
    }
    return;
  }

  // reg block: reuse feature LDS for DFL expectations after all reads complete
  float* g_lds = (float*)lds_feat;  // [4][80]
  __syncthreads();

  if (wave < 4) {
    // reg logits (ch 81..144) + DFL expectation for side f = wave
    const float projscale = 16.f / 15.f;
    #pragma unroll
    for (int mf = 0; mf < 5; ++mf) {
      const int m = mf * 16 + col;
      f32x4 v = acc[mf] + bias;
      float* dst = out + (outbase + m) * 149 + 81 + wave * 16 + quad * 4;
      __builtin_memcpy(dst, &v, 16);
      // softmax over 16 bins: 4 regs x 4 quads (same m column)
      float mx = fmaxf(fmaxf(v[0], v[1]), fmaxf(v[2], v[3]));
      mx = fmaxf(mx, __shfl_xor(mx, 16, 64));
      mx = fmaxf(mx, __shfl_xor(mx, 32, 64));
      const float e0 = __expf(v[0] - mx), e1 = __expf(v[1] - mx);
      const float e2 = __expf(v[2] - mx), e3 = __expf(v[3] - mx);
      float sden = e0 + e1 + e2 + e3;
      const float q4 = (float)(quad * 4);
      float n = q4 * e0 + (q4 + 1.f) * e1 + (q4 + 2.f) * e2 + (q4 + 3.f) * e3;
      sden += __shfl_xor(sden, 16, 64); sden += __shfl_xor(sden, 32, 64);
      n    += __shfl_xor(n, 16, 64);    n    += __shfl_xor(n, 32, 64);
      if (quad == 0) g_lds[wave * 80 + m] = projscale * n / sden;
    }
  } else {
    // wave 4: obj row (o=64 -> quad 0, reg 0)
    #pragma unroll
    for (int mf = 0; mf < 5; ++mf) {
      const int m = mf * 16 + col;
      if (quad == 0) out[(outbase + m) * 149] = acc[mf][0] + bias[0];
    }
  }

  __syncthreads();

  // box decode (wave 4): anchors +/- expectation * stride, m = 0..79
  if (wave == 4) {
    #pragma unroll
    for (int it = 0; it < 2; ++it) {
      const int m = it * 64 + lane;
      if (m < 80) {
        const float g0 = g_lds[m], g1 = g_lds[80 + m];
        const float g2 = g_lds[160 + m], g3 = g_lds[240 + m];
        const int mg = m0 + m;
        int hh;
        if (level == 0)      hh = mg / 80;
        else if (level == 1) hh = mg / 40;
        else                 hh = mg / 20;
        const int ww = mg - hh * LW_[level];
        const float ax = (ww + 0.5f) * strd;
        const float ay = (hh + 0.5f) * strd;
        f32x4 bv;
        bv[0] = ax - g0 * strd; bv[1] = ay - g1 * strd;
        bv[2] = ax + g2 * strd; bv[3] = ay + g3 * strd;
        float* dst = out + (outbase + m) * 149 + 145;
        __builtin_memcpy(dst, &bv, 16);
      }
    }
  }
}

extern "C" void kernel_launch(void* const* d_in, const int* in_sizes, int n_in,
                              void* d_out, int out_size, void* d_ws, size_t ws_size,
                              hipStream_t stream) {
  (void)in_sizes; (void)n_in; (void)out_size; (void)d_ws; (void)ws_size;
  Params p;
  p.cls_feat[0] = (const float*)d_in[0];
  p.reg_feat[0] = (const float*)d_in[1];
  p.cls_feat[1] = (const float*)d_in[2];
  p.reg_feat[1] = (const float*)d_in[3];
  p.cls_feat[2] = (const float*)d_in[4];
  p.reg_feat[2] = (const float*)d_in[5];
  for (int l = 0; l < 3; ++l) {
    const int base = 6 + l * 6;
    p.obj_w[l] = (const float*)d_in[base + 0];
    p.obj_b[l] = (const float*)d_in[base + 1];
    p.cls_w[l] = (const float*)d_in[base + 2];
    p.cls_b[l] = (const float*)d_in[base + 3];
    p.reg_w[l] = (const float*)d_in[base + 4];
    p.reg_b[l] = (const float*)d_in[base + 5];
  }
  p.out = (float*)d_out;

  dim3 grid(16 * 105, 2);  // x: batch*tile (80+20+5 per batch), y: 0=cls, 1=reg/obj
  dim3 block(320);         // 5 waves, one 16-row o-tile each
  hipLaunchKernelGGL(head_kernel, grid, block, 0, stream, p);
}